// Round 7
// baseline (13098.578 us; speedup 1.0000x reference)
//
#include <hip/hip_runtime.h>
#include <hip/hip_bf16.h>
#include <cstddef>

#define BB 16
#define TT 32
#define VV 1003
#define EE 100
#define HH 2048
#define G4 8192  // 4*H

typedef __attribute__((ext_vector_type(8))) short s16x8;
typedef __attribute__((ext_vector_type(4))) float f32x4;

__device__ __forceinline__ unsigned short f2bf(float f) {
  unsigned u = __float_as_uint(f);
  u += 0x7fffu + ((u >> 16) & 1u);
  return (unsigned short)(u >> 16);
}
__device__ __forceinline__ float bf2f(unsigned short s) {
  return __uint_as_float(((unsigned)s) << 16);
}

// ---------------- embedding gather -> A-fragments (hi/lo bf16) ---------------
__global__ __launch_bounds__(256) void embed_frag(
    const int* __restrict__ tokens, const float* __restrict__ emb,
    short* __restrict__ xf) {
  int i = blockIdx.x * 256 + threadIdx.x;   // 32t * 16b * 128e
  if (i >= TT * BB * 128) return;
  int e = i & 127, b = (i >> 7) & 15, t = i >> 11;
  float v = 0.f;
  if (e < EE) v = emb[(size_t)tokens[b * TT + t] * EE + e];
  unsigned short hi = f2bf(v);
  unsigned short lo = f2bf(v - bf2f(hi));
  int kt = e >> 5, kk = e & 31;
  int lane = (kk >> 3) * 16 + b, j = kk & 7;
  size_t idx = (size_t)t * 4096 + ((size_t)kt * 64 + lane) * 8 + j;
  xf[idx] = (short)hi;
  xf[idx + 2048] = (short)lo;
}

// ---------------- pre-split fp32 matrix -> permuted B-fragments (hi+lo) ------
__global__ __launch_bounds__(256) void split_matrix(
    const float* __restrict__ src, short* __restrict__ dst,
    int Kreal, int nkt, int sh) {
  int tid = threadIdx.x, w = tid >> 6, L = tid & 63;
  int tile = blockIdx.x * 4 + w;
  int ct = tile >> sh, kt = tile & (nkt - 1);
  int cl = L & 15;
  int gcol = (cl >> 2) * HH + ct * 4 + (cl & 3);
  int r0 = kt * 32 + (L >> 4) * 8;
  s16x8 hh, ll;
#pragma unroll
  for (int j = 0; j < 8; j++) {
    int r = r0 + j;
    float v = (r < Kreal) ? src[(size_t)r * G4 + gcol] : 0.f;
    unsigned short h = f2bf(v);
    hh[j] = (short)h;
    ll[j] = (short)f2bf(v - bf2f(h));
  }
  size_t base = ((size_t)tile) * 1024 + L * 8;
  *(s16x8*)&dst[base] = hh;
  *(s16x8*)&dst[base + 512] = ll;
}

// ---------------- pre-split U -> compact hi-only B-fragments -----------------
__global__ __launch_bounds__(256) void split_matrix_hi(
    const float* __restrict__ src, short* __restrict__ dst) {
  int tid = threadIdx.x, w = tid >> 6, L = tid & 63;
  int tile = blockIdx.x * 4 + w;
  int ct = tile >> 6, kt = tile & 63;
  int cl = L & 15;
  int gcol = (cl >> 2) * HH + ct * 4 + (cl & 3);
  int r0 = kt * 32 + (L >> 4) * 8;
  s16x8 hh;
#pragma unroll
  for (int j = 0; j < 8; j++) {
    float v = src[(size_t)(r0 + j) * G4 + gcol];
    hh[j] = (short)f2bf(v);
  }
  *(s16x8*)&dst[(size_t)tile * 512 + L * 8] = hh;
}

// ---------------- MFMA GEMM: xz (permuted cols) = A @ W + bias --------------
// M-tile 64 (4 t), N-tile 128 (8 ct). grid (64, 8) = 512 blocks, 2/CU.
__global__ __launch_bounds__(256) void gemm_mfma(
    const short* __restrict__ af, int lo_off, int t_stride, int nkt,
    const short* __restrict__ wfrag, const float* __restrict__ bias,
    float* __restrict__ xz) {
  __shared__ __align__(16) short Bs[8][1024];
  int tid = threadIdx.x;
  int w = tid >> 6, L = tid & 63;
  int ct0 = blockIdx.x * 8;
  int t_a = blockIdx.y * 4 + w;

  f32x4 acc[8];
#pragma unroll
  for (int nt = 0; nt < 8; nt++) acc[nt] = (f32x4){0.f, 0.f, 0.f, 0.f};
  const short* Ah = af + (size_t)t_a * t_stride + L * 8;

  for (int kt = 0; kt < nkt; kt++) {
    s16x8 tmp[4];
#pragma unroll
    for (int q = 0; q < 4; q++) {
      int chunk = q * 256 + tid;
      int nt = chunk >> 7, idx = chunk & 127;
      tmp[q] = *(const s16x8*)&wfrag[((size_t)(ct0 + nt) * nkt + kt) * 1024 + idx * 8];
    }
    __syncthreads();
#pragma unroll
    for (int q = 0; q < 4; q++) {
      int chunk = q * 256 + tid;
      int nt = chunk >> 7, idx = chunk & 127;
      *(s16x8*)&Bs[nt][idx * 8] = tmp[q];
    }
    __syncthreads();

    s16x8 aH = *(const s16x8*)(Ah + kt * 512);
    s16x8 aL = *(const s16x8*)(Ah + lo_off + kt * 512);
#pragma unroll
    for (int nt = 0; nt < 8; nt++) {
      s16x8 bH = *(const s16x8*)&Bs[nt][L * 8];
      s16x8 bL = *(const s16x8*)&Bs[nt][512 + L * 8];
      acc[nt] = __builtin_amdgcn_mfma_f32_16x16x32_bf16(aH, bH, acc[nt], 0, 0, 0);
      acc[nt] = __builtin_amdgcn_mfma_f32_16x16x32_bf16(aL, bH, acc[nt], 0, 0, 0);
      acc[nt] = __builtin_amdgcn_mfma_f32_16x16x32_bf16(aH, bL, acc[nt], 0, 0, 0);
    }
  }

  int nq = L >> 4, hl = L & 15;
#pragma unroll
  for (int nt = 0; nt < 8; nt++) {
    int ctg = ct0 + nt;
    int gcol = (hl >> 2) * HH + ctg * 4 + (hl & 3);
    float bv = bias[gcol];
#pragma unroll
    for (int r = 0; r < 4; r++) {
      int b = nq * 4 + r;
      xz[((size_t)t_a * 16 + b) * G4 + ctg * 16 + hl] = acc[nt][r] + bv;
    }
  }
}

// ---------------- persistent per-layer LSTM --------------------------------
// grid 256 (block owns 2 col-tiles = 8 hu), 1024 thr = 16 waves.
// U slice (128 KB) cached in LDS; h,c state in LDS; grid barrier between steps.
__global__ __launch_bounds__(1024, 4) void lstm_layer(
    const short* __restrict__ Ufrag,   // compact hi tiles [ct*64+kt][512]
    const float* __restrict__ xz,      // [32][16][8192] permuted cols
    short* __restrict__ hfs,           // 33 slots x 65536 shorts
    float* __restrict__ hT_final,      // [2048][16]
    const int* __restrict__ tokens,
    unsigned* __restrict__ bar) {      // 8 counters, 32-uint spacing
  __shared__ __align__(16) short Ush[2 * 64 * 512];  // 128 KB
  __shared__ float red[16][16][16];                   // 16 KB
  __shared__ float zs[2][16][16];
  __shared__ float hc[2][2][16][4];                   // [c/h][ctl][b][hq]
  int tid = threadIdx.x, w = tid >> 6, L = tid & 63;
  int ct0 = blockIdx.x * 2;

  {  // stage U tiles for both col-tiles (contiguous 128 KB)
    const s16x8* src = (const s16x8*)(Ufrag + (size_t)ct0 * 64 * 512);
    s16x8* dst = (s16x8*)Ush;
    for (int i = tid; i < 2 * 64 * 64; i += 1024) dst[i] = src[i];
  }
  if (tid < 256) ((float*)hc)[tid] = 0.f;
  __syncthreads();

  const int kq = w * 4;  // wave's 4 k-frags
  for (int t = 0; t < TT; t++) {
    const short* Hb = hfs + (size_t)t * 65536 + (size_t)kq * 512 + L * 8;
    const short* U0 = Ush + kq * 512 + L * 8;
    f32x4 a0 = {0.f, 0.f, 0.f, 0.f}, a1 = {0.f, 0.f, 0.f, 0.f};
#pragma unroll
    for (int i = 0; i < 4; i++) {
      s16x8 ah = *(const s16x8*)(Hb + i * 512);
      s16x8 al = *(const s16x8*)(Hb + i * 512 + 32768);
      s16x8 b0 = *(const s16x8*)(U0 + i * 512);
      s16x8 b1 = *(const s16x8*)(U0 + 32768 + i * 512);
      a0 = __builtin_amdgcn_mfma_f32_16x16x32_bf16(ah, b0, a0, 0, 0, 0);
      a0 = __builtin_amdgcn_mfma_f32_16x16x32_bf16(al, b0, a0, 0, 0, 0);
      a1 = __builtin_amdgcn_mfma_f32_16x16x32_bf16(ah, b1, a1, 0, 0, 0);
      a1 = __builtin_amdgcn_mfma_f32_16x16x32_bf16(al, b1, a1, 0, 0, 0);
    }
    // reduce ct0
#pragma unroll
    for (int r = 0; r < 4; r++) red[w][(L >> 4) * 4 + r][L & 15] = a0[r];
    __syncthreads();
    if (tid < 256) {
      int b = tid >> 4, cl = tid & 15;
      float s = 0.f;
#pragma unroll
      for (int q = 0; q < 16; q++) s += red[q][b][cl];
      zs[0][b][cl] = s + xz[((size_t)t * 16 + b) * G4 + (ct0 + 0) * 16 + cl];
    }
    __syncthreads();
    // reduce ct0+1
#pragma unroll
    for (int r = 0; r < 4; r++) red[w][(L >> 4) * 4 + r][L & 15] = a1[r];
    __syncthreads();
    if (tid < 256) {
      int b = tid >> 4, cl = tid & 15;
      float s = 0.f;
#pragma unroll
      for (int q = 0; q < 16; q++) s += red[q][b][cl];
      zs[1][b][cl] = s + xz[((size_t)t * 16 + b) * G4 + (ct0 + 1) * 16 + cl];
    }
    __syncthreads();

    if (tid < 128) {
      int ctl = tid >> 6, r2 = tid & 63;
      int b = r2 >> 2, hq = r2 & 3;
      int hu = (ct0 + ctl) * 4 + hq;
      float z0 = zs[ctl][b][0 + hq];
      float z1 = zs[ctl][b][4 + hq];
      float z2 = zs[ctl][b][8 + hq];
      float z3 = zs[ctl][b][12 + hq];
      float ig = 1.f / (1.f + expf(-z0));
      float fg = 1.f / (1.f + expf(-z1));
      float gt = tanhf(z2);
      float og = 1.f / (1.f + expf(-z3));
      float c_old = hc[0][ctl][b][hq];
      float h_old = hc[1][ctl][b][hq];
      float cn = fg * c_old + ig * gt;
      float hn = og * tanhf(cn);
      if (tokens[b * TT + t] == 0) {
        cn = c_old;
        hn = h_old;
      }
      hc[0][ctl][b][hq] = cn;
      hc[1][ctl][b][hq] = hn;
      unsigned short hi = f2bf(hn);
      unsigned short lo = f2bf(hn - bf2f(hi));
      int kt2 = hu >> 5, kk = hu & 31;
      int lane2 = (kk >> 3) * 16 + b, jj = kk & 7;
      size_t idx = ((size_t)kt2 * 64 + lane2) * 8 + jj;
      short* o = hfs + (size_t)(t + 1) * 65536;
      o[idx] = (short)hi;
      o[idx + 32768] = (short)lo;
      if (t == TT - 1) hT_final[(size_t)hu * BB + b] = hn;
    }

    if (t < TT - 1) {  // grid barrier (skip after last step)
      __threadfence();
      __syncthreads();
      if (tid == 0) {
        __hip_atomic_fetch_add(&bar[(blockIdx.x & 7) * 32], 1u,
                               __ATOMIC_RELEASE, __HIP_MEMORY_SCOPE_AGENT);
        unsigned target = (unsigned)(t + 1) * 256;
        for (;;) {
          unsigned s = 0;
#pragma unroll
          for (int i = 0; i < 8; i++)
            s += __hip_atomic_load(&bar[i * 32], __ATOMIC_RELAXED,
                                   __HIP_MEMORY_SCOPE_AGENT);
          if (s >= target) break;
          __builtin_amdgcn_s_sleep(2);
        }
      }
      __syncthreads();
      __threadfence();
    }
  }
}

// ---------------- head stage 1: K-split partial GEMM -------------------------
__global__ __launch_bounds__(256) void head_partial(
    const float* __restrict__ XT, const float* __restrict__ W,
    float* __restrict__ partial, int N) {
  __shared__ float xs[4096];  // 256 k x 16 b
  int tid = threadIdx.x;
  int k0 = blockIdx.y * 256;
  const float* src = XT + (size_t)k0 * 16;
  for (int i = tid; i < 4096; i += 256) xs[i] = src[i];
  __syncthreads();
  int kg = tid >> 6, lane = tid & 63;
  int col = blockIdx.x * 64 + lane;
  if (col >= N) return;
  float acc[16];
#pragma unroll
  for (int b = 0; b < 16; b++) acc[b] = 0.f;
  const float* Wp = W + (size_t)(k0 + kg * 64) * N + col;
  const float* xp = xs + kg * 64 * 16;
  for (int kk = 0; kk < 64; kk++) {
    float wv = Wp[(size_t)kk * N];
#pragma unroll
    for (int b = 0; b < 16; b++) acc[b] = fmaf(xp[kk * 16 + b], wv, acc[b]);
  }
  int chunk = blockIdx.y * 4 + kg;
#pragma unroll
  for (int b = 0; b < 16; b++)
    partial[((size_t)chunk * 16 + b) * N + col] = acc[b];
}

// ---------------- head stage 2: reduce 32 chunks + bias ----------------------
__global__ __launch_bounds__(256) void head_reduce(
    const float* __restrict__ partial, const float* __restrict__ bias,
    float* __restrict__ out, int N, int sc, int sb) {
  int i = blockIdx.x * 256 + threadIdx.x;
  if (i >= 16 * N) return;
  int b = i / N, col = i - b * N;
  float s = bias[col];
#pragma unroll 8
  for (int ch = 0; ch < 32; ch++) s += partial[((size_t)ch * 16 + b) * N + col];
  out[(size_t)col * sc + (size_t)b * sb] = s;
}

// ---------------- softmax over rows of [16][1003] ----------------
__global__ __launch_bounds__(256) void softmax_rows(
    const float* __restrict__ logits, float* __restrict__ out, int N) {
  __shared__ float buf[1024];
  __shared__ float wred[4];
  __shared__ float rmax, rsum;
  int b = blockIdx.x, tid = threadIdx.x;
  float m = -1e30f;
  for (int v = tid; v < N; v += 256) {
    float x = logits[(size_t)b * N + v];
    buf[v] = x;
    m = fmaxf(m, x);
  }
  for (int o = 32; o > 0; o >>= 1) m = fmaxf(m, __shfl_down(m, o, 64));
  if ((tid & 63) == 0) wred[tid >> 6] = m;
  __syncthreads();
  if (tid == 0) rmax = fmaxf(fmaxf(wred[0], wred[1]), fmaxf(wred[2], wred[3]));
  __syncthreads();
  float s = 0.f;
  for (int v = tid; v < N; v += 256) {
    float e = expf(buf[v] - rmax);
    buf[v] = e;
    s += e;
  }
  for (int o = 32; o > 0; o >>= 1) s += __shfl_down(s, o, 64);
  if ((tid & 63) == 0) wred[tid >> 6] = s;
  __syncthreads();
  if (tid == 0) rsum = wred[0] + wred[1] + wred[2] + wred[3];
  __syncthreads();
  float inv = 1.f / rsum;
  for (int v = tid; v < N; v += 256) out[(size_t)b * N + v] = buf[v] * inv;
}

extern "C" void kernel_launch(void* const* d_in, const int* in_sizes, int n_in,
                              void* d_out, int out_size, void* d_ws, size_t ws_size,
                              hipStream_t stream) {
  const int*   tokens = (const int*)d_in[0];
  const float* emb  = (const float*)d_in[1];
  const float* W1   = (const float*)d_in[2];
  const float* U1   = (const float*)d_in[3];
  const float* b1   = (const float*)d_in[4];
  const float* W2   = (const float*)d_in[5];
  const float* U2   = (const float*)d_in[6];
  const float* b2   = (const float*)d_in[7];
  const float* W3   = (const float*)d_in[8];
  const float* U3   = (const float*)d_in[9];
  const float* b3   = (const float*)d_in[10];
  const float* Wd1  = (const float*)d_in[11];
  const float* bd1  = (const float*)d_in[12];
  const float* Wd2  = (const float*)d_in[13];
  const float* bd2  = (const float*)d_in[14];
  float* out = (float*)d_out;

  char* base = (char*)d_ws;
  size_t off = 0;
  auto carve = [&](size_t bytes) -> char* {
    char* p = base + off;
    off += (bytes + 255) & ~(size_t)255;
    return p;
  };
  float* xz      = (float*)carve((size_t)TT * BB * G4 * 4);     // 16 MB
  short* allhf0  = (short*)carve(33ull * 65536 * 2);            // 4.33 MB
  short* allhf1  = (short*)carve(33ull * 65536 * 2);
  short* allhf2  = (short*)carve(33ull * 65536 * 2);
  short* xfrag   = (short*)carve((size_t)TT * 4096 * 2);        // 256 KB
  short* frag    = (short*)carve(512ull * 64 * 1024 * 2);       // 64 MB shared W/U frags
  float* hT0     = (float*)carve(HH * BB * 4);                  // final h
  float* yT      = (float*)carve(HH * BB * 4);
  float* logits  = (float*)carve(BB * 1024 * 4);
  float* partial = (float*)carve(32ull * 16 * HH * 4);          // 4 MB head partials
  unsigned* bar  = (unsigned*)carve(3 * 256 * 4);               // barrier counters

  short* allhf[3] = {allhf0, allhf1, allhf2};
  const float* Us[3] = {U1, U2, U3};
  const float* Ws[3] = {W1, W2, W3};
  const float* bs[3] = {b1, b2, b3};

  (void)hipMemsetAsync(bar, 0, 3 * 256 * 4, stream);
  embed_frag<<<dim3(256), 256, 0, stream>>>(tokens, emb, xfrag);

  for (int layer = 0; layer < 3; layer++) {
    const short* af;
    int lo_off, t_stride, nktW, KrealW;
    if (layer == 0) {
      af = xfrag; lo_off = 2048; t_stride = 4096; nktW = 4; KrealW = EE;
    } else {
      af = allhf[layer - 1] + 65536;  // slot 1 == h at t=0
      lo_off = 32768; t_stride = 65536; nktW = 64; KrealW = HH;
    }
    int shW = (nktW == 4) ? 2 : 6;
    split_matrix<<<dim3(512 * nktW / 4), 256, 0, stream>>>(
        Ws[layer], frag, KrealW, nktW, shW);
    gemm_mfma<<<dim3(64, 8), 256, 0, stream>>>(
        af, lo_off, t_stride, nktW, frag, bs[layer], xz);
    // compact hi-only U frags (overwrite W frags; stream-ordered after gemm)
    split_matrix_hi<<<dim3(512 * 64 / 4), 256, 0, stream>>>(Us[layer], frag);

    (void)hipMemsetAsync(allhf[layer], 0, 65536 * 2, stream);   // h frag slot 0
    lstm_layer<<<dim3(256), 1024, 0, stream>>>(
        frag, xz, allhf[layer], hT0, tokens, bar + layer * 256);
  }

  // final h (t=31) is in hT0
  head_partial<<<dim3(HH / 64, 8), 256, 0, stream>>>(hT0, Wd1, partial, HH);
  head_reduce<<<dim3((16 * HH + 255) / 256), 256, 0, stream>>>(partial, bd1, yT, HH, 16, 1);
  head_partial<<<dim3((VV + 63) / 64, 8), 256, 0, stream>>>(yT, Wd2, partial, VV);
  head_reduce<<<dim3((16 * VV + 255) / 256), 256, 0, stream>>>(partial, bd2, logits, VV, 1, VV);
  softmax_rows<<<dim3(BB), 256, 0, stream>>>(logits, out, VV);
}

// Round 8
// 1084.859 us; speedup vs baseline: 12.0740x; 12.0740x over previous
//
#include <hip/hip_runtime.h>
#include <hip/hip_bf16.h>
#include <cstddef>

#define BB 16
#define TT 32
#define VV 1003
#define EE 100
#define HH 2048
#define G4 8192  // 4*H

typedef __attribute__((ext_vector_type(8))) short s16x8;
typedef __attribute__((ext_vector_type(4))) float f32x4;

__device__ __forceinline__ unsigned short f2bf(float f) {
  unsigned u = __float_as_uint(f);
  u += 0x7fffu + ((u >> 16) & 1u);
  return (unsigned short)(u >> 16);
}
__device__ __forceinline__ float bf2f(unsigned short s) {
  return __uint_as_float(((unsigned)s) << 16);
}

// ---------------- embedding gather -> A-fragments (hi/lo bf16) ---------------
__global__ __launch_bounds__(256) void embed_frag(
    const int* __restrict__ tokens, const float* __restrict__ emb,
    short* __restrict__ xf) {
  int i = blockIdx.x * 256 + threadIdx.x;   // 32t * 16b * 128e
  if (i >= TT * BB * 128) return;
  int e = i & 127, b = (i >> 7) & 15, t = i >> 11;
  float v = 0.f;
  if (e < EE) v = emb[(size_t)tokens[b * TT + t] * EE + e];
  unsigned short hi = f2bf(v);
  unsigned short lo = f2bf(v - bf2f(hi));
  int kt = e >> 5, kk = e & 31;
  int lane = (kk >> 3) * 16 + b, j = kk & 7;
  size_t idx = (size_t)t * 4096 + ((size_t)kt * 64 + lane) * 8 + j;
  xf[idx] = (short)hi;
  xf[idx + 2048] = (short)lo;
}

// ---------------- pre-split fp32 matrix -> permuted hi-only B-fragments ------
// tile = ct*nkt + kt; frag = 512 shorts. cols permuted: cl=(g*4+hq) -> g*HH+ct*4+hq
__global__ __launch_bounds__(256) void split_hi(
    const float* __restrict__ src, short* __restrict__ dst,
    int Kreal, int nkt, int sh) {
  int tid = threadIdx.x, w = tid >> 6, L = tid & 63;
  int tile = blockIdx.x * 4 + w;
  int ct = tile >> sh, kt = tile & (nkt - 1);
  int cl = L & 15;
  int gcol = (cl >> 2) * HH + ct * 4 + (cl & 3);
  int r0 = kt * 32 + (L >> 4) * 8;
  s16x8 hh;
#pragma unroll
  for (int j = 0; j < 8; j++) {
    int r = r0 + j;
    float v = (r < Kreal) ? src[(size_t)r * G4 + gcol] : 0.f;
    hh[j] = (short)f2bf(v);
  }
  *(s16x8*)&dst[(size_t)tile * 512 + L * 8] = hh;
}

// ---------------- MFMA GEMM: xz (permuted cols) = A @ W + bias --------------
// A hi/lo frags, W hi-only frags. M-tile 64 (4 t), N-tile 128 (8 ct), BK=64.
// grid (64, 8) = 512 blocks.
__global__ __launch_bounds__(256) void gemm_mfma(
    const short* __restrict__ af, int lo_off, int t_stride, int nkt,
    const short* __restrict__ wfrag, const float* __restrict__ bias,
    float* __restrict__ xz) {
  __shared__ __align__(16) short Bs[2][8][512];  // 16 KB
  int tid = threadIdx.x;
  int w = tid >> 6, L = tid & 63;
  int ct0 = blockIdx.x * 8;
  int t_a = blockIdx.y * 4 + w;

  f32x4 acc[8];
#pragma unroll
  for (int nt = 0; nt < 8; nt++) acc[nt] = (f32x4){0.f, 0.f, 0.f, 0.f};
  const short* Ah = af + (size_t)t_a * t_stride + L * 8;

  for (int kt0 = 0; kt0 < nkt; kt0 += 2) {
    // stage 16 tiles (8 ct x 2 kt) = 16 KB in 4 passes
    s16x8 tmp[4];
#pragma unroll
    for (int q = 0; q < 4; q++) {
      int idx = q * 256 + tid;           // [0,1024)
      int tl = idx >> 6;                 // 0..15
      int nt = tl >> 1, kk = tl & 1;
      tmp[q] = *(const s16x8*)&wfrag[((size_t)(ct0 + nt) * nkt + kt0 + kk) * 512 + (idx & 63) * 8];
    }
    __syncthreads();
#pragma unroll
    for (int q = 0; q < 4; q++) {
      int idx = q * 256 + tid;
      int tl = idx >> 6;
      int nt = tl >> 1, kk = tl & 1;
      *(s16x8*)&Bs[kk][nt][(idx & 63) * 8] = tmp[q];
    }
    __syncthreads();

#pragma unroll
    for (int kk = 0; kk < 2; kk++) {
      s16x8 aH = *(const s16x8*)(Ah + (kt0 + kk) * 512);
      s16x8 aL = *(const s16x8*)(Ah + lo_off + (kt0 + kk) * 512);
#pragma unroll
      for (int nt = 0; nt < 8; nt++) {
        s16x8 bH = *(const s16x8*)&Bs[kk][nt][L * 8];
        acc[nt] = __builtin_amdgcn_mfma_f32_16x16x32_bf16(aH, bH, acc[nt], 0, 0, 0);
        acc[nt] = __builtin_amdgcn_mfma_f32_16x16x32_bf16(aL, bH, acc[nt], 0, 0, 0);
      }
    }
  }

  int nq = L >> 4, hl = L & 15;
#pragma unroll
  for (int nt = 0; nt < 8; nt++) {
    int ctg = ct0 + nt;
    int gcol = (hl >> 2) * HH + ctg * 4 + (hl & 3);
    float bv = bias[gcol];
#pragma unroll
    for (int r = 0; r < 4; r++) {
      int b = nq * 4 + r;
      xz[((size_t)t_a * 16 + b) * G4 + ctg * 16 + hl] = acc[nt][r] + bv;
    }
  }
}

// ---------------- one LSTM step, fused, hi-only U frags, 8 waves -------------
// grid 512 (1 col-tile = 4 hu x 4 gates each), 512 thr = 8 waves (8 k-frags ea).
__global__ __launch_bounds__(512, 4) void lstm_step(
    const short* __restrict__ Ufrag,   // compact hi tiles [ct*64+kt][512]
    const float* __restrict__ xzt,     // [16][8192] permuted cols
    const short* __restrict__ hf_in,   // slot t  (A-frags hi/lo)
    short* __restrict__ hf_out,        // slot t+1
    const float* __restrict__ hT_in,   // [2048][16] fp32
    float* __restrict__ hT_out,
    float* __restrict__ c,             // [16][2048]
    const int* __restrict__ tokens, int t) {
  __shared__ float red[8][16][16];     // 8 KB
  __shared__ float zs[16][16];
  int tid = threadIdx.x, w = tid >> 6, L = tid & 63;
  int ct = blockIdx.x;

  // early prefetches (hide L2/L3 latency under the MFMA phase)
  float xzv = 0.f;
  if (tid < 256) xzv = xzt[(size_t)(tid >> 4) * G4 + ct * 16 + (tid & 15)];
  float c_old = 0.f, h_old = 0.f;
  int tok = 1;
  if (tid < 64) {
    int b = tid >> 2, hq = tid & 3;
    int hu = ct * 4 + hq;
    c_old = c[(size_t)b * HH + hu];
    h_old = hT_in[(size_t)hu * BB + b];
    tok = tokens[b * TT + t];
  }

  f32x4 acc = {0.f, 0.f, 0.f, 0.f};
  const short* Ub = Ufrag + ((size_t)ct * 64 + w * 8) * 512 + L * 8;
  const short* Hb = hf_in + (size_t)(w * 8) * 512 + L * 8;

#pragma unroll
  for (int i = 0; i < 8; i++) {
    s16x8 bh = *(const s16x8*)(Ub + i * 512);
    s16x8 ah = *(const s16x8*)(Hb + i * 512);
    s16x8 al = *(const s16x8*)(Hb + i * 512 + 32768);
    acc = __builtin_amdgcn_mfma_f32_16x16x32_bf16(ah, bh, acc, 0, 0, 0);
    acc = __builtin_amdgcn_mfma_f32_16x16x32_bf16(al, bh, acc, 0, 0, 0);
  }
#pragma unroll
  for (int r = 0; r < 4; r++) red[w][(L >> 4) * 4 + r][L & 15] = acc[r];
  __syncthreads();

  if (tid < 256) {
    int b = tid >> 4, cl = tid & 15;
    float s = xzv;
#pragma unroll
    for (int q = 0; q < 8; q++) s += red[q][b][cl];
    zs[b][cl] = s;
  }
  __syncthreads();

  if (tid < 64) {
    int b = tid >> 2, hq = tid & 3;
    int hu = ct * 4 + hq;
    float z0 = zs[b][0 + hq];
    float z1 = zs[b][4 + hq];
    float z2 = zs[b][8 + hq];
    float z3 = zs[b][12 + hq];
    float ig = 1.f / (1.f + expf(-z0));
    float fg = 1.f / (1.f + expf(-z1));
    float gt = tanhf(z2);
    float og = 1.f / (1.f + expf(-z3));
    float cn = fg * c_old + ig * gt;
    float hn = og * tanhf(cn);
    if (tok == 0) {
      cn = c_old;
      hn = h_old;
    }
    c[(size_t)b * HH + hu] = cn;
    hT_out[(size_t)hu * BB + b] = hn;
    unsigned short hi = f2bf(hn);
    unsigned short lo = f2bf(hn - bf2f(hi));
    int kt2 = hu >> 5, kk = hu & 31;
    int lane2 = (kk >> 3) * 16 + b, jj = kk & 7;
    size_t idx = ((size_t)kt2 * 64 + lane2) * 8 + jj;
    hf_out[idx] = (short)hi;
    hf_out[idx + 32768] = (short)lo;
  }
}

// ---------------- head stage 1: K-split partial GEMM -------------------------
__global__ __launch_bounds__(256) void head_partial(
    const float* __restrict__ XT, const float* __restrict__ W,
    float* __restrict__ partial, int N) {
  __shared__ float xs[4096];  // 256 k x 16 b
  int tid = threadIdx.x;
  int k0 = blockIdx.y * 256;
  const float* src = XT + (size_t)k0 * 16;
  for (int i = tid; i < 4096; i += 256) xs[i] = src[i];
  __syncthreads();
  int kg = tid >> 6, lane = tid & 63;
  int col = blockIdx.x * 64 + lane;
  if (col >= N) return;
  float acc[16];
#pragma unroll
  for (int b = 0; b < 16; b++) acc[b] = 0.f;
  const float* Wp = W + (size_t)(k0 + kg * 64) * N + col;
  const float* xp = xs + kg * 64 * 16;
  for (int kk = 0; kk < 64; kk++) {
    float wv = Wp[(size_t)kk * N];
#pragma unroll
    for (int b = 0; b < 16; b++) acc[b] = fmaf(xp[kk * 16 + b], wv, acc[b]);
  }
  int chunk = blockIdx.y * 4 + kg;
#pragma unroll
  for (int b = 0; b < 16; b++)
    partial[((size_t)chunk * 16 + b) * N + col] = acc[b];
}

// ---------------- head stage 2: reduce 32 chunks + bias ----------------------
__global__ __launch_bounds__(256) void head_reduce(
    const float* __restrict__ partial, const float* __restrict__ bias,
    float* __restrict__ out, int N, int sc, int sb) {
  int i = blockIdx.x * 256 + threadIdx.x;
  if (i >= 16 * N) return;
  int b = i / N, col = i - b * N;
  float s = bias[col];
#pragma unroll 8
  for (int ch = 0; ch < 32; ch++) s += partial[((size_t)ch * 16 + b) * N + col];
  out[(size_t)col * sc + (size_t)b * sb] = s;
}

// ---------------- softmax over rows of [16][1003] ----------------
__global__ __launch_bounds__(256) void softmax_rows(
    const float* __restrict__ logits, float* __restrict__ out, int N) {
  __shared__ float buf[1024];
  __shared__ float wred[4];
  __shared__ float rmax, rsum;
  int b = blockIdx.x, tid = threadIdx.x;
  float m = -1e30f;
  for (int v = tid; v < N; v += 256) {
    float x = logits[(size_t)b * N + v];
    buf[v] = x;
    m = fmaxf(m, x);
  }
  for (int o = 32; o > 0; o >>= 1) m = fmaxf(m, __shfl_down(m, o, 64));
  if ((tid & 63) == 0) wred[tid >> 6] = m;
  __syncthreads();
  if (tid == 0) rmax = fmaxf(fmaxf(wred[0], wred[1]), fmaxf(wred[2], wred[3]));
  __syncthreads();
  float s = 0.f;
  for (int v = tid; v < N; v += 256) {
    float e = expf(buf[v] - rmax);
    buf[v] = e;
    s += e;
  }
  for (int o = 32; o > 0; o >>= 1) s += __shfl_down(s, o, 64);
  if ((tid & 63) == 0) wred[tid >> 6] = s;
  __syncthreads();
  if (tid == 0) rsum = wred[0] + wred[1] + wred[2] + wred[3];
  __syncthreads();
  float inv = 1.f / rsum;
  for (int v = tid; v < N; v += 256) out[(size_t)b * N + v] = buf[v] * inv;
}

extern "C" void kernel_launch(void* const* d_in, const int* in_sizes, int n_in,
                              void* d_out, int out_size, void* d_ws, size_t ws_size,
                              hipStream_t stream) {
  const int*   tokens = (const int*)d_in[0];
  const float* emb  = (const float*)d_in[1];
  const float* W1   = (const float*)d_in[2];
  const float* U1   = (const float*)d_in[3];
  const float* b1   = (const float*)d_in[4];
  const float* W2   = (const float*)d_in[5];
  const float* U2   = (const float*)d_in[6];
  const float* b2   = (const float*)d_in[7];
  const float* W3   = (const float*)d_in[8];
  const float* U3   = (const float*)d_in[9];
  const float* b3   = (const float*)d_in[10];
  const float* Wd1  = (const float*)d_in[11];
  const float* bd1  = (const float*)d_in[12];
  const float* Wd2  = (const float*)d_in[13];
  const float* bd2  = (const float*)d_in[14];
  float* out = (float*)d_out;

  char* base = (char*)d_ws;
  size_t off = 0;
  auto carve = [&](size_t bytes) -> char* {
    char* p = base + off;
    off += (bytes + 255) & ~(size_t)255;
    return p;
  };
  float* xz      = (float*)carve((size_t)TT * BB * G4 * 4);     // 16 MB
  short* allhf0  = (short*)carve(33ull * 65536 * 2);            // 4.33 MB
  short* allhf1  = (short*)carve(33ull * 65536 * 2);
  short* allhf2  = (short*)carve(33ull * 65536 * 2);
  short* xfrag   = (short*)carve((size_t)TT * 4096 * 2);        // 256 KB
  short* wfrag   = (short*)carve(512ull * 64 * 512 * 2);        // 32 MB W hi-frags
  short* ufrag   = (short*)carve(512ull * 64 * 512 * 2);        // 32 MB U hi-frags
  float* hT0     = (float*)carve(2 * HH * BB * 4);              // hT0 + c contiguous
  float* cbuf    = hT0 + HH * BB;
  float* hT1     = (float*)carve(HH * BB * 4);
  float* yT      = (float*)carve(HH * BB * 4);
  float* logits  = (float*)carve(BB * 1024 * 4);
  float* partial = (float*)carve(32ull * 16 * HH * 4);          // 4 MB head partials

  short* allhf[3] = {allhf0, allhf1, allhf2};
  const float* Us[3] = {U1, U2, U3};
  const float* Ws[3] = {W1, W2, W3};
  const float* bs[3] = {b1, b2, b3};
  float* hping[2] = {hT0, hT1};

  embed_frag<<<dim3(256), 256, 0, stream>>>(tokens, emb, xfrag);

  for (int layer = 0; layer < 3; layer++) {
    const short* af;
    int lo_off, t_stride, nktW, KrealW;
    if (layer == 0) {
      af = xfrag; lo_off = 2048; t_stride = 4096; nktW = 4; KrealW = EE;
    } else {
      af = allhf[layer - 1] + 65536;  // slot 1 == h at t=0
      lo_off = 32768; t_stride = 65536; nktW = 64; KrealW = HH;
    }
    int shW = (nktW == 4) ? 2 : 6;
    split_hi<<<dim3(512 * nktW / 4), 256, 0, stream>>>(
        Ws[layer], wfrag, KrealW, nktW, shW);
    gemm_mfma<<<dim3(64, 8), 256, 0, stream>>>(
        af, lo_off, t_stride, nktW, wfrag, bs[layer], xz);
    split_hi<<<dim3(512 * 64 / 4), 256, 0, stream>>>(Us[layer], ufrag, HH, 64, 6);

    (void)hipMemsetAsync(allhf[layer], 0, 65536 * 2, stream);   // h frag slot 0
    (void)hipMemsetAsync(hT0, 0, 2 * HH * BB * 4, stream);      // hT0 + c
    for (int t = 0; t < TT; t++) {
      lstm_step<<<dim3(512), 512, 0, stream>>>(
          ufrag, xz + (size_t)t * BB * G4,
          allhf[layer] + (size_t)t * 65536, allhf[layer] + (size_t)(t + 1) * 65536,
          hping[t & 1], hping[(t + 1) & 1], cbuf, tokens, t);
    }
  }

  // final h (t=31) is in hT0
  head_partial<<<dim3(HH / 64, 8), 256, 0, stream>>>(hT0, Wd1, partial, HH);
  head_reduce<<<dim3((16 * HH + 255) / 256), 256, 0, stream>>>(partial, bd1, yT, HH, 16, 1);
  head_partial<<<dim3((VV + 63) / 64, 8), 256, 0, stream>>>(yT, Wd2, partial, VV);
  head_reduce<<<dim3((16 * VV + 255) / 256), 256, 0, stream>>>(partial, bd2, logits, VV, 1, VV);
  softmax_rows<<<dim3(BB), 256, 0, stream>>>(logits, out, VV);
}

// Round 9
// 1000.507 us; speedup vs baseline: 13.0919x; 1.0843x over previous
//
#include <hip/hip_runtime.h>
#include <hip/hip_bf16.h>
#include <cstddef>

#define BB 16
#define TT 32
#define VV 1003
#define EE 100
#define HH 2048
#define G4 8192  // 4*H

typedef __attribute__((ext_vector_type(8))) short s16x8;
typedef __attribute__((ext_vector_type(4))) float f32x4;

__device__ __forceinline__ unsigned short f2bf(float f) {
  unsigned u = __float_as_uint(f);
  u += 0x7fffu + ((u >> 16) & 1u);
  return (unsigned short)(u >> 16);
}

// ---------------- embedding gather -> hi-only A-fragments -------------------
// xf per t: [4 kt][64 lane][8] shorts (t stride 2048)
__global__ __launch_bounds__(256) void embed_frag(
    const int* __restrict__ tokens, const float* __restrict__ emb,
    short* __restrict__ xf) {
  int i = blockIdx.x * 256 + threadIdx.x;   // 32t * 16b * 128e
  if (i >= TT * BB * 128) return;
  int e = i & 127, b = (i >> 7) & 15, t = i >> 11;
  float v = 0.f;
  if (e < EE) v = emb[(size_t)tokens[b * TT + t] * EE + e];
  int kt = e >> 5, kk = e & 31;
  int lane = (kk >> 3) * 16 + b, j = kk & 7;
  xf[(size_t)t * 2048 + ((size_t)kt * 64 + lane) * 8 + j] = (short)f2bf(v);
}

// ---------------- pre-split fp32 matrix -> permuted hi-only B-fragments ------
// tile = ct*nkt + kt; frag = 512 shorts. cols permuted: cl=(g*4+hq) -> g*HH+ct*4+hq
__global__ __launch_bounds__(256) void split_hi(
    const float* __restrict__ src, short* __restrict__ dst,
    int Kreal, int nkt, int sh) {
  int tid = threadIdx.x, w = tid >> 6, L = tid & 63;
  int tile = blockIdx.x * 4 + w;
  int ct = tile >> sh, kt = tile & (nkt - 1);
  int cl = L & 15;
  int gcol = (cl >> 2) * HH + ct * 4 + (cl & 3);
  int r0 = kt * 32 + (L >> 4) * 8;
  s16x8 hh;
#pragma unroll
  for (int j = 0; j < 8; j++) {
    int r = r0 + j;
    float v = (r < Kreal) ? src[(size_t)r * G4 + gcol] : 0.f;
    hh[j] = (short)f2bf(v);
  }
  *(s16x8*)&dst[(size_t)tile * 512 + L * 8] = hh;
}

// ---------------- MFMA GEMM: xz (permuted cols) = A @ W + bias --------------
// A hi-only frags, W hi-only frags. M-tile 64 (4 t), N-tile 128 (8 ct), BK=64.
// Double-buffered LDS: one barrier per K-iter. grid (64, 8) = 512 blocks.
__global__ __launch_bounds__(256) void gemm_mfma(
    const short* __restrict__ af, int t_stride, int nkt,
    const short* __restrict__ wfrag, const float* __restrict__ bias,
    float* __restrict__ xz) {
  __shared__ __align__(16) short Bs[2][2][8][512];  // 32 KB
  int tid = threadIdx.x;
  int w = tid >> 6, L = tid & 63;
  int ct0 = blockIdx.x * 8;
  int t_a = blockIdx.y * 4 + w;

  f32x4 acc[8];
#pragma unroll
  for (int nt = 0; nt < 8; nt++) acc[nt] = (f32x4){0.f, 0.f, 0.f, 0.f};
  const short* Ah = af + (size_t)t_a * t_stride + L * 8;

  s16x8 tmp[4];
  // load first 2-kt stage
#pragma unroll
  for (int q = 0; q < 4; q++) {
    int idx = q * 256 + tid;
    int tl = idx >> 6, nt = tl >> 1, kk = tl & 1;
    tmp[q] = *(const s16x8*)&wfrag[((size_t)(ct0 + nt) * nkt + kk) * 512 + (idx & 63) * 8];
  }
#pragma unroll
  for (int q = 0; q < 4; q++) {
    int idx = q * 256 + tid;
    int tl = idx >> 6, nt = tl >> 1, kk = tl & 1;
    *(s16x8*)&Bs[0][kk][nt][(idx & 63) * 8] = tmp[q];
  }
  __syncthreads();

  int cur = 0;
  for (int kt0 = 0; kt0 < nkt; kt0 += 2) {
    if (kt0 + 2 < nkt) {
#pragma unroll
      for (int q = 0; q < 4; q++) {
        int idx = q * 256 + tid;
        int tl = idx >> 6, nt = tl >> 1, kk = tl & 1;
        tmp[q] = *(const s16x8*)&wfrag[((size_t)(ct0 + nt) * nkt + kt0 + 2 + kk) * 512 + (idx & 63) * 8];
      }
    }
#pragma unroll
    for (int kk = 0; kk < 2; kk++) {
      s16x8 aH = *(const s16x8*)(Ah + (kt0 + kk) * 512);
#pragma unroll
      for (int nt = 0; nt < 8; nt++) {
        s16x8 bH = *(const s16x8*)&Bs[cur][kk][nt][L * 8];
        acc[nt] = __builtin_amdgcn_mfma_f32_16x16x32_bf16(aH, bH, acc[nt], 0, 0, 0);
      }
    }
    if (kt0 + 2 < nkt) {
#pragma unroll
      for (int q = 0; q < 4; q++) {
        int idx = q * 256 + tid;
        int tl = idx >> 6, nt = tl >> 1, kk = tl & 1;
        *(s16x8*)&Bs[cur ^ 1][kk][nt][(idx & 63) * 8] = tmp[q];
      }
      __syncthreads();
      cur ^= 1;
    }
  }

  int nq = L >> 4, hl = L & 15;
#pragma unroll
  for (int nt = 0; nt < 8; nt++) {
    int ctg = ct0 + nt;
    int gcol = (hl >> 2) * HH + ctg * 4 + (hl & 3);
    float bv = bias[gcol];
#pragma unroll
    for (int r = 0; r < 4; r++) {
      int b = nq * 4 + r;
      xz[((size_t)t_a * 16 + b) * G4 + ctg * 16 + hl] = acc[nt][r] + bv;
    }
  }
}

// ---------------- one LSTM step, fused, all-hi bf16, 8 waves -----------------
// grid 512 (1 col-tile = 4 hu x 4 gates each), 512 thr = 8 waves (8 k-frags ea).
__global__ __launch_bounds__(512, 4) void lstm_step(
    const short* __restrict__ Ufrag,   // hi tiles [ct*64+kt][512]
    const float* __restrict__ xzt,     // [16][8192] permuted cols
    const short* __restrict__ hf_in,   // slot t (hi A-frags, 32768 shorts)
    short* __restrict__ hf_out,        // slot t+1
    const float* __restrict__ hT_in,   // [2048][16] fp32
    float* __restrict__ hT_out,
    float* __restrict__ c,             // [16][2048]
    const int* __restrict__ tokens, int t) {
  __shared__ float red[8][16][16];     // 8 KB
  __shared__ float zs[16][16];
  int tid = threadIdx.x, w = tid >> 6, L = tid & 63;
  int ct = blockIdx.x;

  // early prefetches (hide L2/L3 latency under the MFMA phase)
  float xzv = 0.f;
  if (tid < 256) xzv = xzt[(size_t)(tid >> 4) * G4 + ct * 16 + (tid & 15)];
  float c_old = 0.f, h_old = 0.f;
  int tok = 1;
  if (tid < 64) {
    int b = tid >> 2, hq = tid & 3;
    int hu = ct * 4 + hq;
    c_old = c[(size_t)b * HH + hu];
    h_old = hT_in[(size_t)hu * BB + b];
    tok = tokens[b * TT + t];
  }

  f32x4 acc = {0.f, 0.f, 0.f, 0.f};
  const short* Ub = Ufrag + ((size_t)ct * 64 + w * 8) * 512 + L * 8;
  const short* Hb = hf_in + (size_t)(w * 8) * 512 + L * 8;

#pragma unroll
  for (int i = 0; i < 8; i++) {
    s16x8 bh = *(const s16x8*)(Ub + i * 512);
    s16x8 ah = *(const s16x8*)(Hb + i * 512);
    acc = __builtin_amdgcn_mfma_f32_16x16x32_bf16(ah, bh, acc, 0, 0, 0);
  }
#pragma unroll
  for (int r = 0; r < 4; r++) red[w][(L >> 4) * 4 + r][L & 15] = acc[r];
  __syncthreads();

  if (tid < 256) {
    int b = tid >> 4, cl = tid & 15;
    float s = xzv;
#pragma unroll
    for (int q = 0; q < 8; q++) s += red[q][b][cl];
    zs[b][cl] = s;
  }
  __syncthreads();

  if (tid < 64) {
    int b = tid >> 2, hq = tid & 3;
    int hu = ct * 4 + hq;
    float z0 = zs[b][0 + hq];
    float z1 = zs[b][4 + hq];
    float z2 = zs[b][8 + hq];
    float z3 = zs[b][12 + hq];
    float ig = 1.f / (1.f + expf(-z0));
    float fg = 1.f / (1.f + expf(-z1));
    float gt = tanhf(z2);
    float og = 1.f / (1.f + expf(-z3));
    float cn = fg * c_old + ig * gt;
    float hn = og * tanhf(cn);
    if (tok == 0) {
      cn = c_old;
      hn = h_old;
    }
    c[(size_t)b * HH + hu] = cn;
    hT_out[(size_t)hu * BB + b] = hn;
    int kt2 = hu >> 5, kk = hu & 31;
    int lane2 = (kk >> 3) * 16 + b, jj = kk & 7;
    hf_out[((size_t)kt2 * 64 + lane2) * 8 + jj] = (short)f2bf(hn);
  }
}

// ---------------- head stage 1: K-split partial GEMM -------------------------
__global__ __launch_bounds__(256) void head_partial(
    const float* __restrict__ XT, const float* __restrict__ W,
    float* __restrict__ partial, int N) {
  __shared__ float xs[4096];  // 256 k x 16 b
  int tid = threadIdx.x;
  int k0 = blockIdx.y * 256;
  const float* src = XT + (size_t)k0 * 16;
  for (int i = tid; i < 4096; i += 256) xs[i] = src[i];
  __syncthreads();
  int kg = tid >> 6, lane = tid & 63;
  int col = blockIdx.x * 64 + lane;
  if (col >= N) return;
  float acc[16];
#pragma unroll
  for (int b = 0; b < 16; b++) acc[b] = 0.f;
  const float* Wp = W + (size_t)(k0 + kg * 64) * N + col;
  const float* xp = xs + kg * 64 * 16;
  for (int kk = 0; kk < 64; kk++) {
    float wv = Wp[(size_t)kk * N];
#pragma unroll
    for (int b = 0; b < 16; b++) acc[b] = fmaf(xp[kk * 16 + b], wv, acc[b]);
  }
  int chunk = blockIdx.y * 4 + kg;
#pragma unroll
  for (int b = 0; b < 16; b++)
    partial[((size_t)chunk * 16 + b) * N + col] = acc[b];
}

// ---------------- head stage 2: reduce 32 chunks + bias ----------------------
__global__ __launch_bounds__(256) void head_reduce(
    const float* __restrict__ partial, const float* __restrict__ bias,
    float* __restrict__ out, int N, int sc, int sb) {
  int i = blockIdx.x * 256 + threadIdx.x;
  if (i >= 16 * N) return;
  int b = i / N, col = i - b * N;
  float s = bias[col];
#pragma unroll 8
  for (int ch = 0; ch < 32; ch++) s += partial[((size_t)ch * 16 + b) * N + col];
  out[(size_t)col * sc + (size_t)b * sb] = s;
}

// ---------------- softmax over rows of [16][1003] ----------------
__global__ __launch_bounds__(256) void softmax_rows(
    const float* __restrict__ logits, float* __restrict__ out, int N) {
  __shared__ float buf[1024];
  __shared__ float wred[4];
  __shared__ float rmax, rsum;
  int b = blockIdx.x, tid = threadIdx.x;
  float m = -1e30f;
  for (int v = tid; v < N; v += 256) {
    float x = logits[(size_t)b * N + v];
    buf[v] = x;
    m = fmaxf(m, x);
  }
  for (int o = 32; o > 0; o >>= 1) m = fmaxf(m, __shfl_down(m, o, 64));
  if ((tid & 63) == 0) wred[tid >> 6] = m;
  __syncthreads();
  if (tid == 0) rmax = fmaxf(fmaxf(wred[0], wred[1]), fmaxf(wred[2], wred[3]));
  __syncthreads();
  float s = 0.f;
  for (int v = tid; v < N; v += 256) {
    float e = expf(buf[v] - rmax);
    buf[v] = e;
    s += e;
  }
  for (int o = 32; o > 0; o >>= 1) s += __shfl_down(s, o, 64);
  if ((tid & 63) == 0) wred[tid >> 6] = s;
  __syncthreads();
  if (tid == 0) rsum = wred[0] + wred[1] + wred[2] + wred[3];
  __syncthreads();
  float inv = 1.f / rsum;
  for (int v = tid; v < N; v += 256) out[(size_t)b * N + v] = buf[v] * inv;
}

extern "C" void kernel_launch(void* const* d_in, const int* in_sizes, int n_in,
                              void* d_out, int out_size, void* d_ws, size_t ws_size,
                              hipStream_t stream) {
  const int*   tokens = (const int*)d_in[0];
  const float* emb  = (const float*)d_in[1];
  const float* W1   = (const float*)d_in[2];
  const float* U1   = (const float*)d_in[3];
  const float* b1   = (const float*)d_in[4];
  const float* W2   = (const float*)d_in[5];
  const float* U2   = (const float*)d_in[6];
  const float* b2   = (const float*)d_in[7];
  const float* W3   = (const float*)d_in[8];
  const float* U3   = (const float*)d_in[9];
  const float* b3   = (const float*)d_in[10];
  const float* Wd1  = (const float*)d_in[11];
  const float* bd1  = (const float*)d_in[12];
  const float* Wd2  = (const float*)d_in[13];
  const float* bd2  = (const float*)d_in[14];
  float* out = (float*)d_out;

  char* base = (char*)d_ws;
  size_t off = 0;
  auto carve = [&](size_t bytes) -> char* {
    char* p = base + off;
    off += (bytes + 255) & ~(size_t)255;
    return p;
  };
  float* xz      = (float*)carve((size_t)TT * BB * G4 * 4);     // 16 MB
  short* allhf0  = (short*)carve(33ull * 32768 * 2);            // 2.16 MB
  short* allhf1  = (short*)carve(33ull * 32768 * 2);
  short* allhf2  = (short*)carve(33ull * 32768 * 2);
  short* xfrag   = (short*)carve((size_t)TT * 2048 * 2);        // 128 KB
  short* wfrag   = (short*)carve(512ull * 64 * 512 * 2);        // 32 MB W hi-frags
  short* ufrag   = (short*)carve(512ull * 64 * 512 * 2);        // 32 MB U hi-frags
  float* hT0     = (float*)carve(2 * HH * BB * 4);              // hT0 + c contiguous
  float* cbuf    = hT0 + HH * BB;
  float* hT1     = (float*)carve(HH * BB * 4);
  float* yT      = (float*)carve(HH * BB * 4);
  float* logits  = (float*)carve(BB * 1024 * 4);
  float* partial = (float*)carve(32ull * 16 * HH * 4);          // 4 MB head partials

  short* allhf[3] = {allhf0, allhf1, allhf2};
  const float* Us[3] = {U1, U2, U3};
  const float* Ws[3] = {W1, W2, W3};
  const float* bs[3] = {b1, b2, b3};
  float* hping[2] = {hT0, hT1};

  embed_frag<<<dim3(256), 256, 0, stream>>>(tokens, emb, xfrag);

  for (int layer = 0; layer < 3; layer++) {
    const short* af;
    int t_stride, nktW, KrealW;
    if (layer == 0) {
      af = xfrag; t_stride = 2048; nktW = 4; KrealW = EE;
    } else {
      af = allhf[layer - 1] + 32768;  // slot 1 == h at t=0
      t_stride = 32768; nktW = 64; KrealW = HH;
    }
    int shW = (nktW == 4) ? 2 : 6;
    split_hi<<<dim3(512 * nktW / 4), 256, 0, stream>>>(
        Ws[layer], wfrag, KrealW, nktW, shW);
    gemm_mfma<<<dim3(64, 8), 256, 0, stream>>>(
        af, t_stride, nktW, wfrag, bs[layer], xz);
    split_hi<<<dim3(512 * 64 / 4), 256, 0, stream>>>(Us[layer], ufrag, HH, 64, 6);

    (void)hipMemsetAsync(allhf[layer], 0, 32768 * 2, stream);   // h frag slot 0
    (void)hipMemsetAsync(hT0, 0, 2 * HH * BB * 4, stream);      // hT0 + c
    for (int t = 0; t < TT; t++) {
      lstm_step<<<dim3(512), 512, 0, stream>>>(
          ufrag, xz + (size_t)t * BB * G4,
          allhf[layer] + (size_t)t * 32768, allhf[layer] + (size_t)(t + 1) * 32768,
          hping[t & 1], hping[(t + 1) & 1], cbuf, tokens, t);
    }
  }

  // final h (t=31) is in hT0
  head_partial<<<dim3(HH / 64, 8), 256, 0, stream>>>(hT0, Wd1, partial, HH);
  head_reduce<<<dim3((16 * HH + 255) / 256), 256, 0, stream>>>(partial, bd1, yT, HH, 16, 1);
  head_partial<<<dim3((VV + 63) / 64, 8), 256, 0, stream>>>(yT, Wd2, partial, VV);
  head_reduce<<<dim3((16 * VV + 255) / 256), 256, 0, stream>>>(partial, bd2, logits, VV, 1, VV);
  softmax_rows<<<dim3(BB), 256, 0, stream>>>(logits, out, VV);
}

// Round 11
// 772.473 us; speedup vs baseline: 16.9567x; 1.2952x over previous
//
#include <hip/hip_runtime.h>
#include <hip/hip_bf16.h>
#include <cstddef>

#define BB 16
#define TT 32
#define VV 1003
#define EE 100
#define HH 2048
#define G4 8192  // 4*H

typedef __attribute__((ext_vector_type(4))) float f32x4;
typedef unsigned char u8;

#define SA 64.0f        // A-side (x, h) scale
#define SB 128.0f       // B-side (W, U) scale
#define DESCALE 1.220703125e-4f  // 1/8192

__device__ __forceinline__ unsigned pk_lo(unsigned old, float a, float b) {
  return (unsigned)__builtin_amdgcn_cvt_pk_fp8_f32(a, b, (int)old, false);
}
__device__ __forceinline__ unsigned pk_hi(unsigned old, float a, float b) {
  return (unsigned)__builtin_amdgcn_cvt_pk_fp8_f32(a, b, (int)old, true);
}
__device__ __forceinline__ u8 cvt1fp8(float a) {
  return (u8)(__builtin_amdgcn_cvt_pk_fp8_f32(a, 0.f, 0, false) & 0xff);
}

// ---------------- embedding gather -> fp8 A-fragments ------------------------
// xf per t: [4 kt][64 lane][8] bytes (t stride 2048 B)
__global__ __launch_bounds__(256) void embed_frag(
    const int* __restrict__ tokens, const float* __restrict__ emb,
    u8* __restrict__ xf) {
  int i = blockIdx.x * 256 + threadIdx.x;   // 32t * 16b * 128e
  if (i >= TT * BB * 128) return;
  int e = i & 127, b = (i >> 7) & 15, t = i >> 11;
  float v = 0.f;
  if (e < EE) v = emb[(size_t)tokens[b * TT + t] * EE + e] * SA;
  int kt = e >> 5, kk = e & 31;
  int lane = (kk >> 3) * 16 + b, j = kk & 7;
  xf[(size_t)t * 2048 + ((size_t)kt * 64 + lane) * 8 + j] = cvt1fp8(v);
}

// ---------------- pre-split fp32 matrix -> permuted fp8 B-fragments ----------
// tile = ct*nkt + kt; frag = 512 bytes. cols permuted: cl=(g*4+hq) -> g*HH+ct*4+hq
__global__ __launch_bounds__(256) void split_fp8(
    const float* __restrict__ src, u8* __restrict__ dst,
    int Kreal, int nkt, int sh) {
  int tid = threadIdx.x, w = tid >> 6, L = tid & 63;
  int tile = blockIdx.x * 4 + w;
  int ct = tile >> sh, kt = tile & (nkt - 1);
  int cl = L & 15;
  int gcol = (cl >> 2) * HH + ct * 4 + (cl & 3);
  int r0 = kt * 32 + (L >> 4) * 8;
  float v[8];
#pragma unroll
  for (int j = 0; j < 8; j++) {
    int r = r0 + j;
    v[j] = (r < Kreal) ? src[(size_t)r * G4 + gcol] * SB : 0.f;
  }
  unsigned lo = 0, hi = 0;
  lo = pk_lo(lo, v[0], v[1]);
  lo = pk_hi(lo, v[2], v[3]);
  hi = pk_lo(hi, v[4], v[5]);
  hi = pk_hi(hi, v[6], v[7]);
  *(uint2*)&dst[(size_t)tile * 512 + L * 8] = make_uint2(lo, hi);
}

// ---------------- MFMA fp8 GEMM: xz (permuted cols) = A @ W + bias ----------
// M-tile 64 (4 t), N-tile 128 (8 ct), BK=64 (2 kt/stage), 3-stage LDS pipeline.
// 512 threads = 8 waves: wave w -> t_a = by*4 + (w&3), nt range (w>>2)*4..+3.
__global__ __launch_bounds__(512) void gemm_mfma(
    const u8* __restrict__ af, int t_stride, int nkt,
    const u8* __restrict__ wfrag, const float* __restrict__ bias,
    float* __restrict__ xz) {
  __shared__ __align__(16) u8 Bs[3][2][8][512];  // 24 KB
  int tid = threadIdx.x;
  int w = tid >> 6, L = tid & 63;
  int ct0 = blockIdx.x * 8;
  int t_a = blockIdx.y * 4 + (w & 3);
  int nt0 = (w >> 2) * 4;

  f32x4 acc[4];
#pragma unroll
  for (int i = 0; i < 4; i++) acc[i] = (f32x4){0.f, 0.f, 0.f, 0.f};
  const u8* Ah = af + (size_t)t_a * t_stride + L * 8;
  int ns = nkt >> 1;

  // stage-loader role: 512 thr x 16 B = 8 KB = one stage (16 tiles x 512 B)
  int tl = tid >> 5, off = (tid & 31) * 16;
  int s_nt = tl >> 1, s_kk = tl & 1;

  {
    uint4 t0 = *(const uint4*)&wfrag[((size_t)(ct0 + s_nt) * nkt + s_kk) * 512 + off];
    *(uint4*)&Bs[0][s_kk][s_nt][off] = t0;
    if (ns > 1) {
      uint4 t1 = *(const uint4*)&wfrag[((size_t)(ct0 + s_nt) * nkt + 2 + s_kk) * 512 + off];
      *(uint4*)&Bs[1][s_kk][s_nt][off] = t1;
    }
  }
  __syncthreads();

  for (int s = 0; s < ns; s++) {
    uint4 nx;
    bool pf = (s + 2 < ns);
    if (pf)
      nx = *(const uint4*)&wfrag[((size_t)(ct0 + s_nt) * nkt + 2 * (s + 2) + s_kk) * 512 + off];
    int buf = s % 3;
#pragma unroll
    for (int kk = 0; kk < 2; kk++) {
      long aH = *(const long*)(Ah + (size_t)(2 * s + kk) * 512);
#pragma unroll
      for (int i = 0; i < 4; i++) {
        long bH = *(const long*)&Bs[buf][kk][nt0 + i][L * 8];
        acc[i] = __builtin_amdgcn_mfma_f32_16x16x32_fp8_fp8(aH, bH, acc[i], 0, 0, 0);
      }
    }
    if (pf) *(uint4*)&Bs[(s + 2) % 3][s_kk][s_nt][off] = nx;
    __syncthreads();
  }

  int nq = L >> 4, hl = L & 15;
#pragma unroll
  for (int i = 0; i < 4; i++) {
    int ctg = ct0 + nt0 + i;
    int gcol = (hl >> 2) * HH + ctg * 4 + (hl & 3);
    float bv = bias[gcol];
#pragma unroll
    for (int r = 0; r < 4; r++) {
      int b = nq * 4 + r;
      xz[((size_t)t_a * 16 + b) * G4 + ctg * 16 + hl] = acc[i][r] * DESCALE + bv;
    }
  }
}

// ---------------- one LSTM step, fused, fp8, 8 waves -------------------------
// grid 512 (1 col-tile = 4 hu x 4 gates each), 512 thr = 8 waves (8 k-frags ea).
__global__ __launch_bounds__(512, 4) void lstm_step(
    const u8* __restrict__ Ufrag,      // fp8 tiles [ct*64+kt][512 B]
    const float* __restrict__ xzt,     // [16][8192] permuted cols, fp32
    const u8* __restrict__ hf_in,      // slot t (fp8 A-frags, 32768 B)
    u8* __restrict__ hf_out,           // slot t+1
    const float* __restrict__ hT_in,   // [2048][16] fp32
    float* __restrict__ hT_out,
    float* __restrict__ c,             // [16][2048]
    const int* __restrict__ tokens, int t) {
  __shared__ float red[8][16][16];     // 8 KB
  __shared__ float zs[16][16];
  int tid = threadIdx.x, w = tid >> 6, L = tid & 63;
  int ct = blockIdx.x;

  // early prefetches (hide L2/L3 latency under the MFMA phase)
  float xzv = 0.f;
  if (tid < 256) xzv = xzt[(size_t)(tid >> 4) * G4 + ct * 16 + (tid & 15)];
  float c_old = 0.f, h_old = 0.f;
  int tok = 1;
  if (tid < 64) {
    int b = tid >> 2, hq = tid & 3;
    int hu = ct * 4 + hq;
    c_old = c[(size_t)b * HH + hu];
    h_old = hT_in[(size_t)hu * BB + b];
    tok = tokens[b * TT + t];
  }

  f32x4 acc = {0.f, 0.f, 0.f, 0.f};
  const u8* Ub = Ufrag + ((size_t)ct * 64 + w * 8) * 512 + L * 8;
  const u8* Hb = hf_in + (size_t)(w * 8) * 512 + L * 8;

#pragma unroll
  for (int i = 0; i < 8; i++) {
    long bh = *(const long*)(Ub + i * 512);
    long ah = *(const long*)(Hb + i * 512);
    acc = __builtin_amdgcn_mfma_f32_16x16x32_fp8_fp8(ah, bh, acc, 0, 0, 0);
  }
#pragma unroll
  for (int r = 0; r < 4; r++) red[w][(L >> 4) * 4 + r][L & 15] = acc[r];
  __syncthreads();

  if (tid < 256) {
    int b = tid >> 4, cl = tid & 15;
    float s = 0.f;
#pragma unroll
    for (int q = 0; q < 8; q++) s += red[q][b][cl];
    zs[b][cl] = s * DESCALE + xzv;
  }
  __syncthreads();

  if (tid < 64) {
    int b = tid >> 2, hq = tid & 3;
    int hu = ct * 4 + hq;
    float z0 = zs[b][0 + hq];
    float z1 = zs[b][4 + hq];
    float z2 = zs[b][8 + hq];
    float z3 = zs[b][12 + hq];
    float ig = 1.f / (1.f + expf(-z0));
    float fg = 1.f / (1.f + expf(-z1));
    float gt = tanhf(z2);
    float og = 1.f / (1.f + expf(-z3));
    float cn = fg * c_old + ig * gt;
    float hn = og * tanhf(cn);
    if (tok == 0) {
      cn = c_old;
      hn = h_old;
    }
    c[(size_t)b * HH + hu] = cn;
    hT_out[(size_t)hu * BB + b] = hn;
    int kt2 = hu >> 5, kk = hu & 31;
    int lane2 = (kk >> 3) * 16 + b, jj = kk & 7;
    hf_out[((size_t)kt2 * 64 + lane2) * 8 + jj] = cvt1fp8(hn * SA);
  }
}

// ---------------- head stage 1: K-split partial GEMM (fp32) ------------------
__global__ __launch_bounds__(256) void head_partial(
    const float* __restrict__ XT, const float* __restrict__ W,
    float* __restrict__ partial, int N) {
  __shared__ float xs[4096];  // 256 k x 16 b
  int tid = threadIdx.x;
  int k0 = blockIdx.y * 256;
  const float* src = XT + (size_t)k0 * 16;
  for (int i = tid; i < 4096; i += 256) xs[i] = src[i];
  __syncthreads();
  int kg = tid >> 6, lane = tid & 63;
  int col = blockIdx.x * 64 + lane;
  if (col >= N) return;
  float acc[16];
#pragma unroll
  for (int b = 0; b < 16; b++) acc[b] = 0.f;
  const float* Wp = W + (size_t)(k0 + kg * 64) * N + col;
  const float* xp = xs + kg * 64 * 16;
  for (int kk = 0; kk < 64; kk++) {
    float wv = Wp[(size_t)kk * N];
#pragma unroll
    for (int b = 0; b < 16; b++) acc[b] = fmaf(xp[kk * 16 + b], wv, acc[b]);
  }
  int chunk = blockIdx.y * 4 + kg;
#pragma unroll
  for (int b = 0; b < 16; b++)
    partial[((size_t)chunk * 16 + b) * N + col] = acc[b];
}

// ---------------- head stage 2: reduce 32 chunks + bias ----------------------
__global__ __launch_bounds__(256) void head_reduce(
    const float* __restrict__ partial, const float* __restrict__ bias,
    float* __restrict__ out, int N, int sc, int sb) {
  int i = blockIdx.x * 256 + threadIdx.x;
  if (i >= 16 * N) return;
  int b = i / N, col = i - b * N;
  float s = bias[col];
#pragma unroll 8
  for (int ch = 0; ch < 32; ch++) s += partial[((size_t)ch * 16 + b) * N + col];
  out[(size_t)col * sc + (size_t)b * sb] = s;
}

// ---------------- softmax over rows of [16][1003] ----------------
__global__ __launch_bounds__(256) void softmax_rows(
    const float* __restrict__ logits, float* __restrict__ out, int N) {
  __shared__ float buf[1024];
  __shared__ float wred[4];
  __shared__ float rmax, rsum;
  int b = blockIdx.x, tid = threadIdx.x;
  float m = -1e30f;
  for (int v = tid; v < N; v += 256) {
    float x = logits[(size_t)b * N + v];
    buf[v] = x;
    m = fmaxf(m, x);
  }
  for (int o = 32; o > 0; o >>= 1) m = fmaxf(m, __shfl_down(m, o, 64));
  if ((tid & 63) == 0) wred[tid >> 6] = m;
  __syncthreads();
  if (tid == 0) rmax = fmaxf(fmaxf(wred[0], wred[1]), fmaxf(wred[2], wred[3]));
  __syncthreads();
  float s = 0.f;
  for (int v = tid; v < N; v += 256) {
    float e = expf(buf[v] - rmax);
    buf[v] = e;
    s += e;
  }
  for (int o = 32; o > 0; o >>= 1) s += __shfl_down(s, o, 64);
  if ((tid & 63) == 0) wred[tid >> 6] = s;
  __syncthreads();
  if (tid == 0) rsum = wred[0] + wred[1] + wred[2] + wred[3];
  __syncthreads();
  float inv = 1.f / rsum;
  for (int v = tid; v < N; v += 256) out[(size_t)b * N + v] = buf[v] * inv;
}

extern "C" void kernel_launch(void* const* d_in, const int* in_sizes, int n_in,
                              void* d_out, int out_size, void* d_ws, size_t ws_size,
                              hipStream_t stream) {
  const int*   tokens = (const int*)d_in[0];
  const float* emb  = (const float*)d_in[1];
  const float* W1   = (const float*)d_in[2];
  const float* U1   = (const float*)d_in[3];
  const float* b1   = (const float*)d_in[4];
  const float* W2   = (const float*)d_in[5];
  const float* U2   = (const float*)d_in[6];
  const float* b2   = (const float*)d_in[7];
  const float* W3   = (const float*)d_in[8];
  const float* U3   = (const float*)d_in[9];
  const float* b3   = (const float*)d_in[10];
  const float* Wd1  = (const float*)d_in[11];
  const float* bd1  = (const float*)d_in[12];
  const float* Wd2  = (const float*)d_in[13];
  const float* bd2  = (const float*)d_in[14];
  float* out = (float*)d_out;

  char* base = (char*)d_ws;
  size_t off = 0;
  auto carve = [&](size_t bytes) -> char* {
    char* p = base + off;
    off += (bytes + 255) & ~(size_t)255;
    return p;
  };
  float* xz      = (float*)carve((size_t)TT * BB * G4 * 4);     // 16 MB
  u8*    allhf0  = (u8*)carve(33ull * 32768);                   // 1.08 MB
  u8*    allhf1  = (u8*)carve(33ull * 32768);
  u8*    allhf2  = (u8*)carve(33ull * 32768);
  u8*    xfrag   = (u8*)carve((size_t)TT * 2048);               // 64 KB
  u8*    wfrag   = (u8*)carve(512ull * 64 * 512);               // 16 MB W fp8 frags
  u8*    ufrag   = (u8*)carve(512ull * 64 * 512);               // 16 MB U fp8 frags
  float* hT0     = (float*)carve(2 * HH * BB * 4);              // hT0 + c contiguous
  float* cbuf    = hT0 + HH * BB;
  float* hT1     = (float*)carve(HH * BB * 4);
  float* yT      = (float*)carve(HH * BB * 4);
  float* logits  = (float*)carve(BB * 1024 * 4);
  float* partial = (float*)carve(32ull * 16 * HH * 4);          // 4 MB head partials

  u8* allhf[3] = {allhf0, allhf1, allhf2};
  const float* Us[3] = {U1, U2, U3};
  const float* Ws[3] = {W1, W2, W3};
  const float* bs[3] = {b1, b2, b3};
  float* hping[2] = {hT0, hT1};

  embed_frag<<<dim3(256), 256, 0, stream>>>(tokens, emb, xfrag);

  for (int layer = 0; layer < 3; layer++) {
    const u8* af;
    int t_stride, nktW, KrealW;
    if (layer == 0) {
      af = xfrag; t_stride = 2048; nktW = 4; KrealW = EE;
    } else {
      af = allhf[layer - 1] + 32768;  // slot 1 == h at t=0
      t_stride = 32768; nktW = 64; KrealW = HH;
    }
    int shW = (nktW == 4) ? 2 : 6;
    split_fp8<<<dim3(512 * nktW / 4), 256, 0, stream>>>(
        Ws[layer], wfrag, KrealW, nktW, shW);
    gemm_mfma<<<dim3(64, 8), 512, 0, stream>>>(
        af, t_stride, nktW, wfrag, bs[layer], xz);
    split_fp8<<<dim3(512 * 64 / 4), 256, 0, stream>>>(Us[layer], ufrag, HH, 64, 6);

    (void)hipMemsetAsync(allhf[layer], 0, 32768, stream);       // h frag slot 0
    (void)hipMemsetAsync(hT0, 0, 2 * HH * BB * 4, stream);      // hT0 + c
    for (int t = 0; t < TT; t++) {
      lstm_step<<<dim3(512), 512, 0, stream>>>(
          ufrag, xz + (size_t)t * BB * G4,
          allhf[layer] + (size_t)t * 32768, allhf[layer] + (size_t)(t + 1) * 32768,
          hping[t & 1], hping[(t + 1) & 1], cbuf, tokens, t);
    }
  }

  // final h (t=31) is in hT0
  head_partial<<<dim3(HH / 64, 8), 256, 0, stream>>>(hT0, Wd1, partial, HH);
  head_reduce<<<dim3((16 * HH + 255) / 256), 256, 0, stream>>>(partial, bd1, yT, HH, 16, 1);
  head_partial<<<dim3((VV + 63) / 64, 8), 256, 0, stream>>>(yT, Wd2, partial, VV);
  head_reduce<<<dim3((16 * VV + 255) / 256), 256, 0, stream>>>(partial, bd2, logits, VV, 1, VV);
  softmax_rows<<<dim3(BB), 256, 0, stream>>>(logits, out, VV);
}

// Round 12
// 667.047 us; speedup vs baseline: 19.6367x; 1.1580x over previous
//
#include <hip/hip_runtime.h>
#include <hip/hip_bf16.h>
#include <cstddef>

#define BB 16
#define TT 32
#define VV 1003
#define EE 100
#define HH 2048
#define G4 8192  // 4*H

typedef __attribute__((ext_vector_type(4))) float f32x4;
typedef unsigned char u8;

#define SA 64.0f        // A-side (x, h) scale
#define SB 128.0f       // B-side (W, U) scale
#define DESCALE 1.220703125e-4f  // 1/8192

__device__ __forceinline__ unsigned pk_lo(unsigned old, float a, float b) {
  return (unsigned)__builtin_amdgcn_cvt_pk_fp8_f32(a, b, (int)old, false);
}
__device__ __forceinline__ unsigned pk_hi(unsigned old, float a, float b) {
  return (unsigned)__builtin_amdgcn_cvt_pk_fp8_f32(a, b, (int)old, true);
}
__device__ __forceinline__ u8 cvt1fp8(float a) {
  return (u8)(__builtin_amdgcn_cvt_pk_fp8_f32(a, 0.f, 0, false) & 0xff);
}

// ---------------- embedding gather -> fp8 A-fragments ------------------------
// xf per t: [4 kt][64 lane][8] bytes (t stride 2048 B)
__global__ __launch_bounds__(256) void embed_frag(
    const int* __restrict__ tokens, const float* __restrict__ emb,
    u8* __restrict__ xf) {
  int i = blockIdx.x * 256 + threadIdx.x;   // 32t * 16b * 128e
  if (i >= TT * BB * 128) return;
  int e = i & 127, b = (i >> 7) & 15, t = i >> 11;
  float v = 0.f;
  if (e < EE) v = emb[(size_t)tokens[b * TT + t] * EE + e] * SA;
  int kt = e >> 5, kk = e & 31;
  int lane = (kk >> 3) * 16 + b, j = kk & 7;
  xf[(size_t)t * 2048 + ((size_t)kt * 64 + lane) * 8 + j] = cvt1fp8(v);
}

// ---------------- coalesced split: fp32 [K][8192] -> permuted fp8 B-frags ----
// grid (nkt, 32): kt = bx, ct group = by*16. Phase 1: stage 32 rows x 256 cols
// (4 gates x 64 cols) coalesced into LDS. Phase 2: emit 16 tiles x 512 B.
__global__ __launch_bounds__(256) void split_fp8(
    const float* __restrict__ src, u8* __restrict__ dst,
    int Kreal, int nkt) {
  __shared__ float ld[32][257];
  int tid = threadIdx.x;
  int kt = blockIdx.x, ct0 = blockIdx.y * 16;
  int r0 = kt * 32;

#pragma unroll
  for (int i = 0; i < 8; i++) {
    int elem = i * 1024 + tid * 4;       // float index (x4)
    int row = elem >> 8, c = elem & 255;
    int g = c >> 6, rel = c & 63;
    int r = r0 + row;
    float4 v = make_float4(0.f, 0.f, 0.f, 0.f);
    if (r < Kreal)
      v = *(const float4*)&src[(size_t)r * G4 + (size_t)g * HH + ct0 * 4 + rel];
    ld[row][c] = v.x; ld[row][c + 1] = v.y;
    ld[row][c + 2] = v.z; ld[row][c + 3] = v.w;
  }
  __syncthreads();

  int L = tid & 63;
  int cl = L & 15, g = cl >> 2, hq = cl & 3;
  int row0 = (L >> 4) * 8;
#pragma unroll
  for (int pass = 0; pass < 4; pass++) {
    int ctr = (tid >> 6) + pass * 4;      // ct_rel 0..15
    int col = g * 64 + ctr * 4 + hq;
    unsigned lo = 0, hi = 0;
    lo = pk_lo(lo, ld[row0 + 0][col] * SB, ld[row0 + 1][col] * SB);
    lo = pk_hi(lo, ld[row0 + 2][col] * SB, ld[row0 + 3][col] * SB);
    hi = pk_lo(hi, ld[row0 + 4][col] * SB, ld[row0 + 5][col] * SB);
    hi = pk_hi(hi, ld[row0 + 6][col] * SB, ld[row0 + 7][col] * SB);
    *(uint2*)&dst[((size_t)(ct0 + ctr) * nkt + kt) * 512 + L * 8] =
        make_uint2(lo, hi);
  }
}

// ---------------- MFMA fp8 GEMM: xz (permuted cols) = A @ W + bias ----------
// M-tile 64 (4 t), N-tile 128 (8 ct), BK=64 (2 kt/stage), 3-stage LDS pipeline.
// 512 threads = 8 waves: wave w -> t_a = by*4 + (w&3), nt range (w>>2)*4..+3.
__global__ __launch_bounds__(512) void gemm_mfma(
    const u8* __restrict__ af, int t_stride, int nkt,
    const u8* __restrict__ wfrag, const float* __restrict__ bias,
    float* __restrict__ xz) {
  __shared__ __align__(16) u8 Bs[3][2][8][512];  // 24 KB
  int tid = threadIdx.x;
  int w = tid >> 6, L = tid & 63;
  int ct0 = blockIdx.x * 8;
  int t_a = blockIdx.y * 4 + (w & 3);
  int nt0 = (w >> 2) * 4;

  f32x4 acc[4];
#pragma unroll
  for (int i = 0; i < 4; i++) acc[i] = (f32x4){0.f, 0.f, 0.f, 0.f};
  const u8* Ah = af + (size_t)t_a * t_stride + L * 8;
  int ns = nkt >> 1;

  // stage-loader role: 512 thr x 16 B = 8 KB = one stage (16 tiles x 512 B)
  int tl = tid >> 5, off = (tid & 31) * 16;
  int s_nt = tl >> 1, s_kk = tl & 1;

  {
    uint4 t0 = *(const uint4*)&wfrag[((size_t)(ct0 + s_nt) * nkt + s_kk) * 512 + off];
    *(uint4*)&Bs[0][s_kk][s_nt][off] = t0;
    if (ns > 1) {
      uint4 t1 = *(const uint4*)&wfrag[((size_t)(ct0 + s_nt) * nkt + 2 + s_kk) * 512 + off];
      *(uint4*)&Bs[1][s_kk][s_nt][off] = t1;
    }
  }
  __syncthreads();

  for (int s = 0; s < ns; s++) {
    uint4 nx;
    bool pf = (s + 2 < ns);
    if (pf)
      nx = *(const uint4*)&wfrag[((size_t)(ct0 + s_nt) * nkt + 2 * (s + 2) + s_kk) * 512 + off];
    int buf = s % 3;
#pragma unroll
    for (int kk = 0; kk < 2; kk++) {
      long aH = *(const long*)(Ah + (size_t)(2 * s + kk) * 512);
#pragma unroll
      for (int i = 0; i < 4; i++) {
        long bH = *(const long*)&Bs[buf][kk][nt0 + i][L * 8];
        acc[i] = __builtin_amdgcn_mfma_f32_16x16x32_fp8_fp8(aH, bH, acc[i], 0, 0, 0);
      }
    }
    if (pf) *(uint4*)&Bs[(s + 2) % 3][s_kk][s_nt][off] = nx;
    __syncthreads();
  }

  int nq = L >> 4, hl = L & 15;
#pragma unroll
  for (int i = 0; i < 4; i++) {
    int ctg = ct0 + nt0 + i;
    int gcol = (hl >> 2) * HH + ctg * 4 + (hl & 3);
    float bv = bias[gcol];
#pragma unroll
    for (int r = 0; r < 4; r++) {
      int b = nq * 4 + r;
      xz[((size_t)t_a * 16 + b) * G4 + ctg * 16 + hl] = acc[i][r] * DESCALE + bv;
    }
  }
}

// ---------------- one LSTM step, fused, fp8, 8 waves -------------------------
// grid 512 (1 col-tile = 4 hu x 4 gates each), 512 thr = 8 waves (8 k-frags ea).
__global__ __launch_bounds__(512, 4) void lstm_step(
    const u8* __restrict__ Ufrag,      // fp8 tiles [ct*64+kt][512 B]
    const float* __restrict__ xzt,     // [16][8192] permuted cols, fp32
    const u8* __restrict__ hf_in,      // slot t (fp8 A-frags, 32768 B)
    u8* __restrict__ hf_out,           // slot t+1
    const float* __restrict__ hT_in,   // [2048][16] fp32
    float* __restrict__ hT_out,
    float* __restrict__ c,             // [16][2048]
    const int* __restrict__ tokens, int t) {
  __shared__ float red[8][16][16];     // 8 KB
  __shared__ float zs[16][16];
  int tid = threadIdx.x, w = tid >> 6, L = tid & 63;
  int ct = blockIdx.x;

  // early prefetches (hide L2/L3 latency under the MFMA phase)
  float xzv = 0.f;
  if (tid < 256) xzv = xzt[(size_t)(tid >> 4) * G4 + ct * 16 + (tid & 15)];
  float c_old = 0.f, h_old = 0.f;
  int tok = 1;
  if (tid < 64) {
    int b = tid >> 2, hq = tid & 3;
    int hu = ct * 4 + hq;
    c_old = c[(size_t)b * HH + hu];
    h_old = hT_in[(size_t)hu * BB + b];
    tok = tokens[b * TT + t];
  }

  f32x4 acc = {0.f, 0.f, 0.f, 0.f};
  const u8* Ub = Ufrag + ((size_t)ct * 64 + w * 8) * 512 + L * 8;
  const u8* Hb = hf_in + (size_t)(w * 8) * 512 + L * 8;

#pragma unroll
  for (int i = 0; i < 8; i++) {
    long bh = *(const long*)(Ub + i * 512);
    long ah = *(const long*)(Hb + i * 512);
    acc = __builtin_amdgcn_mfma_f32_16x16x32_fp8_fp8(ah, bh, acc, 0, 0, 0);
  }
#pragma unroll
  for (int r = 0; r < 4; r++) red[w][(L >> 4) * 4 + r][L & 15] = acc[r];
  __syncthreads();

  if (tid < 256) {
    int b = tid >> 4, cl = tid & 15;
    float s = 0.f;
#pragma unroll
    for (int q = 0; q < 8; q++) s += red[q][b][cl];
    zs[b][cl] = s * DESCALE + xzv;
  }
  __syncthreads();

  if (tid < 64) {
    int b = tid >> 2, hq = tid & 3;
    int hu = ct * 4 + hq;
    float z0 = zs[b][0 + hq];
    float z1 = zs[b][4 + hq];
    float z2 = zs[b][8 + hq];
    float z3 = zs[b][12 + hq];
    float ig = 1.f / (1.f + expf(-z0));
    float fg = 1.f / (1.f + expf(-z1));
    float gt = tanhf(z2);
    float og = 1.f / (1.f + expf(-z3));
    float cn = fg * c_old + ig * gt;
    float hn = og * tanhf(cn);
    if (tok == 0) {
      cn = c_old;
      hn = h_old;
    }
    c[(size_t)b * HH + hu] = cn;
    hT_out[(size_t)hu * BB + b] = hn;
    int kt2 = hu >> 5, kk = hu & 31;
    int lane2 = (kk >> 3) * 16 + b, jj = kk & 7;
    hf_out[((size_t)kt2 * 64 + lane2) * 8 + jj] = cvt1fp8(hn * SA);
  }
}

// ---------------- head stage 1: K-split partial GEMM (fp32) ------------------
__global__ __launch_bounds__(256) void head_partial(
    const float* __restrict__ XT, const float* __restrict__ W,
    float* __restrict__ partial, int N) {
  __shared__ float xs[4096];  // 256 k x 16 b
  int tid = threadIdx.x;
  int k0 = blockIdx.y * 256;
  const float* src = XT + (size_t)k0 * 16;
  for (int i = tid; i < 4096; i += 256) xs[i] = src[i];
  __syncthreads();
  int kg = tid >> 6, lane = tid & 63;
  int col = blockIdx.x * 64 + lane;
  if (col >= N) return;
  float acc[16];
#pragma unroll
  for (int b = 0; b < 16; b++) acc[b] = 0.f;
  const float* Wp = W + (size_t)(k0 + kg * 64) * N + col;
  const float* xp = xs + kg * 64 * 16;
  for (int kk = 0; kk < 64; kk++) {
    float wv = Wp[(size_t)kk * N];
#pragma unroll
    for (int b = 0; b < 16; b++) acc[b] = fmaf(xp[kk * 16 + b], wv, acc[b]);
  }
  int chunk = blockIdx.y * 4 + kg;
#pragma unroll
  for (int b = 0; b < 16; b++)
    partial[((size_t)chunk * 16 + b) * N + col] = acc[b];
}

// ---------------- head stage 2: reduce 32 chunks + bias ----------------------
__global__ __launch_bounds__(256) void head_reduce(
    const float* __restrict__ partial, const float* __restrict__ bias,
    float* __restrict__ out, int N, int sc, int sb) {
  int i = blockIdx.x * 256 + threadIdx.x;
  if (i >= 16 * N) return;
  int b = i / N, col = i - b * N;
  float s = bias[col];
#pragma unroll 8
  for (int ch = 0; ch < 32; ch++) s += partial[((size_t)ch * 16 + b) * N + col];
  out[(size_t)col * sc + (size_t)b * sb] = s;
}

// ---------------- softmax over rows of [16][1003] ----------------
__global__ __launch_bounds__(256) void softmax_rows(
    const float* __restrict__ logits, float* __restrict__ out, int N) {
  __shared__ float buf[1024];
  __shared__ float wred[4];
  __shared__ float rmax, rsum;
  int b = blockIdx.x, tid = threadIdx.x;
  float m = -1e30f;
  for (int v = tid; v < N; v += 256) {
    float x = logits[(size_t)b * N + v];
    buf[v] = x;
    m = fmaxf(m, x);
  }
  for (int o = 32; o > 0; o >>= 1) m = fmaxf(m, __shfl_down(m, o, 64));
  if ((tid & 63) == 0) wred[tid >> 6] = m;
  __syncthreads();
  if (tid == 0) rmax = fmaxf(fmaxf(wred[0], wred[1]), fmaxf(wred[2], wred[3]));
  __syncthreads();
  float s = 0.f;
  for (int v = tid; v < N; v += 256) {
    float e = expf(buf[v] - rmax);
    buf[v] = e;
    s += e;
  }
  for (int o = 32; o > 0; o >>= 1) s += __shfl_down(s, o, 64);
  if ((tid & 63) == 0) wred[tid >> 6] = s;
  __syncthreads();
  if (tid == 0) rsum = wred[0] + wred[1] + wred[2] + wred[3];
  __syncthreads();
  float inv = 1.f / rsum;
  for (int v = tid; v < N; v += 256) out[(size_t)b * N + v] = buf[v] * inv;
}

extern "C" void kernel_launch(void* const* d_in, const int* in_sizes, int n_in,
                              void* d_out, int out_size, void* d_ws, size_t ws_size,
                              hipStream_t stream) {
  const int*   tokens = (const int*)d_in[0];
  const float* emb  = (const float*)d_in[1];
  const float* W1   = (const float*)d_in[2];
  const float* U1   = (const float*)d_in[3];
  const float* b1   = (const float*)d_in[4];
  const float* W2   = (const float*)d_in[5];
  const float* U2   = (const float*)d_in[6];
  const float* b2   = (const float*)d_in[7];
  const float* W3   = (const float*)d_in[8];
  const float* U3   = (const float*)d_in[9];
  const float* b3   = (const float*)d_in[10];
  const float* Wd1  = (const float*)d_in[11];
  const float* bd1  = (const float*)d_in[12];
  const float* Wd2  = (const float*)d_in[13];
  const float* bd2  = (const float*)d_in[14];
  float* out = (float*)d_out;

  char* base = (char*)d_ws;
  size_t off = 0;
  auto carve = [&](size_t bytes) -> char* {
    char* p = base + off;
    off += (bytes + 255) & ~(size_t)255;
    return p;
  };
  float* xz      = (float*)carve((size_t)TT * BB * G4 * 4);     // 16 MB
  u8*    allhf0  = (u8*)carve(33ull * 32768);                   // 1.08 MB
  u8*    allhf1  = (u8*)carve(33ull * 32768);
  u8*    allhf2  = (u8*)carve(33ull * 32768);
  u8*    xfrag   = (u8*)carve((size_t)TT * 2048);               // 64 KB
  u8*    wfrag   = (u8*)carve(512ull * 64 * 512);               // 16 MB W fp8 frags
  u8*    ufrag   = (u8*)carve(512ull * 64 * 512);               // 16 MB U fp8 frags
  float* hT0     = (float*)carve(2 * HH * BB * 4);              // hT0 + c contiguous
  float* cbuf    = hT0 + HH * BB;
  float* hT1     = (float*)carve(HH * BB * 4);
  float* yT      = (float*)carve(HH * BB * 4);
  float* logits  = (float*)carve(BB * 1024 * 4);
  float* partial = (float*)carve(32ull * 16 * HH * 4);          // 4 MB head partials

  u8* allhf[3] = {allhf0, allhf1, allhf2};
  const float* Us[3] = {U1, U2, U3};
  const float* Ws[3] = {W1, W2, W3};
  const float* bs[3] = {b1, b2, b3};
  float* hping[2] = {hT0, hT1};

  embed_frag<<<dim3(256), 256, 0, stream>>>(tokens, emb, xfrag);

  for (int layer = 0; layer < 3; layer++) {
    const u8* af;
    int t_stride, nktW, KrealW;
    if (layer == 0) {
      af = xfrag; t_stride = 2048; nktW = 4; KrealW = EE;
    } else {
      af = allhf[layer - 1] + 32768;  // slot 1 == h at t=0
      t_stride = 32768; nktW = 64; KrealW = HH;
    }
    split_fp8<<<dim3(nktW, 32), 256, 0, stream>>>(Ws[layer], wfrag, KrealW, nktW);
    gemm_mfma<<<dim3(64, 8), 512, 0, stream>>>(
        af, t_stride, nktW, wfrag, bs[layer], xz);
    split_fp8<<<dim3(64, 32), 256, 0, stream>>>(Us[layer], ufrag, HH, 64);

    (void)hipMemsetAsync(allhf[layer], 0, 32768, stream);       // h frag slot 0
    (void)hipMemsetAsync(hT0, 0, 2 * HH * BB * 4, stream);      // hT0 + c
    for (int t = 0; t < TT; t++) {
      lstm_step<<<dim3(512), 512, 0, stream>>>(
          ufrag, xz + (size_t)t * BB * G4,
          allhf[layer] + (size_t)t * 32768, allhf[layer] + (size_t)(t + 1) * 32768,
          hping[t & 1], hping[(t + 1) & 1], cbuf, tokens, t);
    }
  }

  // final h (t=31) is in hT0
  head_partial<<<dim3(HH / 64, 8), 256, 0, stream>>>(hT0, Wd1, partial, HH);
  head_reduce<<<dim3((16 * HH + 255) / 256), 256, 0, stream>>>(partial, bd1, yT, HH, 16, 1);
  head_partial<<<dim3((VV + 63) / 64, 8), 256, 0, stream>>>(yT, Wd2, partial, VV);
  head_reduce<<<dim3((16 * VV + 255) / 256), 256, 0, stream>>>(partial, bd2, logits, VV, 1, VV);
  softmax_rows<<<dim3(BB), 256, 0, stream>>>(logits, out, VV);
}